// Round 9
// baseline (524.839 us; speedup 1.0000x reference)
//
#include <hip/hip_runtime.h>

// Problem constants (B=64, T=512, I=256, H=512)
#define BATCH 64
#define TSTEPS 512
#define IDIM 256
#define HDIM 512
#define MROWS (BATCH * TSTEPS)   // 32768

typedef __attribute__((address_space(1))) const void gvoid;
typedef __attribute__((address_space(3))) void lvoid;

__device__ __forceinline__ void gl2lds16(const void* g, void* l) {
    // async global->LDS, 16B per lane; LDS dest = wave-uniform base + lane*16
    __builtin_amdgcn_global_load_lds((gvoid*)g, (lvoid*)l, 16, 0, 0);
}

// ---------------------------------------------------------------------------
// K0: extract center taps: W1T[i][h] = conv1_w[h][i][1] ([k][n] layout);
//                          W2T[h][j] = conv2_w[j][h][1] ([k][n] layout)
// ---------------------------------------------------------------------------
__global__ void extract_weights(const float* __restrict__ c1w,
                                const float* __restrict__ c2w,
                                float* __restrict__ W1T,
                                float* __restrict__ W2T) {
    int tid = blockIdx.x * 256 + threadIdx.x;
    if (tid < IDIM * HDIM) {
        int i = tid >> 9;          // / 512
        int h = tid & 511;
        W1T[tid] = c1w[(h * IDIM + i) * 3 + 1];
    }
    if (tid < HDIM * HDIM) {
        int h = tid >> 9;
        int j = tid & 511;
        W2T[tid] = c2w[(j * HDIM + h) * 3 + 1];
    }
}

// ---------------------------------------------------------------------------
// G1 GEMM (round-4 shape): BM=BN=128, BK=16, 256 threads, 8x8/thread.
// NUMERICS CONTRACT: one sequential k-ascending fp32 fmaf chain per output.
// ---------------------------------------------------------------------------
#define BM1 128
#define BN1 128
#define BK1 16

__global__ __launch_bounds__(256, 2) void gemm_g1(const float* __restrict__ A,
                                                  const float* __restrict__ BT,
                                                  const float* __restrict__ bias,
                                                  float* __restrict__ C,
                                                  int K) {
    __shared__ __align__(16) float As[BK1 * BM1];   // [k][m]  8 KB
    __shared__ __align__(16) float Bs[BK1 * BN1];   // [k][n]  8 KB

    const int N = HDIM;
    int tid  = threadIdx.x;
    int lane = tid & 63;
    int wave = tid >> 6;
    int row0 = blockIdx.x * BM1;
    int col0 = blockIdx.y * BN1;
    int wm = (wave >> 1) * 64;
    int wn = (wave & 1) * 64;
    int mbase = wm + (lane >> 3) * 8;
    int nbase = wn + (lane & 7) * 8;

    float acc[8][8];
#pragma unroll
    for (int i = 0; i < 8; i++)
#pragma unroll
        for (int j = 0; j < 8; j++) acc[i][j] = 0.0f;

    int ar = tid >> 1;
    int ak = (tid & 1) * 8;
    const float* ap = A + (size_t)(row0 + ar) * K + ak;

    const char* bp = (const char*)(BT + (size_t)(tid >> 5) * N + col0) + (tid & 31) * 16;
    char* bld = (char*)Bs + tid * 16;
    const size_t bRow8 = (size_t)8 * N * sizeof(float);

    for (int k0 = 0; k0 < K; k0 += BK1) {
        gl2lds16(bp, bld);
        gl2lds16(bp + bRow8, bld + 4096);
        float4 a0 = *(const float4*)(ap);
        float4 a1 = *(const float4*)(ap + 4);
        ap += BK1;
        bp += (size_t)BK1 * N * sizeof(float);
        As[(ak + 0) * BM1 + ar] = a0.x;
        As[(ak + 1) * BM1 + ar] = a0.y;
        As[(ak + 2) * BM1 + ar] = a0.z;
        As[(ak + 3) * BM1 + ar] = a0.w;
        As[(ak + 4) * BM1 + ar] = a1.x;
        As[(ak + 5) * BM1 + ar] = a1.y;
        As[(ak + 6) * BM1 + ar] = a1.z;
        As[(ak + 7) * BM1 + ar] = a1.w;
        __syncthreads();

#pragma unroll
        for (int k = 0; k < BK1; k++) {
            float4 av0 = *(const float4*)&As[k * BM1 + mbase];
            float4 av1 = *(const float4*)&As[k * BM1 + mbase + 4];
            float4 bv0 = *(const float4*)&Bs[k * BN1 + nbase];
            float4 bv1 = *(const float4*)&Bs[k * BN1 + nbase + 4];
            float a8[8] = {av0.x, av0.y, av0.z, av0.w, av1.x, av1.y, av1.z, av1.w};
            float b8[8] = {bv0.x, bv0.y, bv0.z, bv0.w, bv1.x, bv1.y, bv1.z, bv1.w};
#pragma unroll
            for (int i = 0; i < 8; i++)
#pragma unroll
                for (int j = 0; j < 8; j++)
                    acc[i][j] = fmaf(a8[i], b8[j], acc[i][j]);
        }
        __syncthreads();
    }

    float bb[8];
#pragma unroll
    for (int j = 0; j < 8; j++) bb[j] = bias[col0 + nbase + j];
#pragma unroll
    for (int i = 0; i < 8; i++) {
        int row = row0 + mbase + i;
        float4* cp = (float4*)&C[(size_t)row * N + col0 + nbase];
        cp[0] = (float4){acc[i][0] + bb[0], acc[i][1] + bb[1],
                         acc[i][2] + bb[2], acc[i][3] + bb[3]};
        cp[1] = (float4){acc[i][4] + bb[4], acc[i][5] + bb[5],
                         acc[i][6] + bb[6], acc[i][7] + bb[7]};
    }
}

// ---------------------------------------------------------------------------
// G2 GEMM, LDS-FREE / SMEM-FREE: C[m][j] = sum_h s1T[h][m] * W2T[h][j].
// R8 diagnosis: SMEM A-loads are UNORDERED on lgkmcnt, so any ds_read
// dependence forces lgkmcnt(0) -> drains the A prefetch every 2 k-steps
// (observed 63% VALUBusy, 200us). Fix: every load is VMEM (in-order vmcnt):
//   - B: lanes own 4 cols -> coalesced global_load_dwordx4 per k-step
//        (B-half = 512 KB, L2-resident; re-read ~2 GB over 35 TB/s L2, ok)
//   - A: 16 wave-uniform rows -> 4x dwordx4 vector loads of the SAME address
//        in all lanes (1 cache line, replicated into VGPRs)
// Rotating 4-slot buffer, prefetch distance 3 -> compiler emits fine-grained
// s_waitcnt vmcnt(15) (in-order!), no barriers (single-wave blocks), no LDS.
// Per k-step: 5 VMEM + 64 v_fma. ~170 VGPR -> launch_bounds(64,2),
// 8 blocks/CU: k-step wall ~256 CU-cyc, window 3*256=768 cyc >= L3 latency
// (s1T just written by scan1 -> L3-resident).
// NUMERICS CONTRACT: one sequential k-ascending fp32 fmaf chain per output.
// ---------------------------------------------------------------------------
#define G2_ROWS 16
#define G2_COLS 256

__global__ __launch_bounds__(64, 2) void gemm_g2(const float* __restrict__ AT,
                                                 const float* __restrict__ BT,
                                                 float* __restrict__ C) {
    const int N = HDIM;      // 512
    const int K = HDIM;      // 512
    int lane  = threadIdx.x;             // 0..63
    int row0  = blockIdx.x * G2_ROWS;    // m-chunk (16 rows)
    int col0  = blockIdx.y * G2_COLS;    // n-chunk (256 cols)
    int lane4 = lane * 4;

    float acc[16][4];
#pragma unroll
    for (int i = 0; i < 16; i++)
#pragma unroll
        for (int j = 0; j < 4; j++) acc[i][j] = 0.0f;

    const float* aBase = AT + row0;              // + k*MROWS (wave-uniform)
    const float* bBase = BT + col0 + lane4;      // + k*N     (coalesced)

    float  a[4][16];   // rotating A slots (slot = k & 3), lane-replicated
    float4 b[4];       // rotating B slots

    // preload k = 0,1,2 into slots 0,1,2
#pragma unroll
    for (int p = 0; p < 3; p++) {
        const float* ap = aBase + (size_t)p * MROWS;
#pragma unroll
        for (int i = 0; i < 16; i += 4) {
            float4 t = *(const float4*)(ap + i);
            a[p][i] = t.x; a[p][i + 1] = t.y; a[p][i + 2] = t.z; a[p][i + 3] = t.w;
        }
        b[p] = *(const float4*)(bBase + (size_t)p * N);
    }

    for (int k0 = 0; k0 < K; k0 += 4) {
#pragma unroll
        for (int u = 0; u < 4; u++) {
            int k  = k0 + u;
            int kp = k + 3; if (kp > K - 1) kp = K - 1;  // clamp: last 3 are dummy
            int slot = (u + 3) & 3;
            // prefetch k+3 (all VMEM, in-order vmcnt)
            const float* ap = aBase + (size_t)kp * MROWS;
#pragma unroll
            for (int i = 0; i < 16; i += 4) {
                float4 t = *(const float4*)(ap + i);
                a[slot][i]     = t.x; a[slot][i + 1] = t.y;
                a[slot][i + 2] = t.z; a[slot][i + 3] = t.w;
            }
            b[slot] = *(const float4*)(bBase + (size_t)kp * N);
            // compute k from slot u (loaded 3 k-steps ago)
            float4 bv = b[u];
#pragma unroll
            for (int i = 0; i < 16; i++) {
                acc[i][0] = fmaf(a[u][i], bv.x, acc[i][0]);
                acc[i][1] = fmaf(a[u][i], bv.y, acc[i][1]);
                acc[i][2] = fmaf(a[u][i], bv.z, acc[i][2]);
                acc[i][3] = fmaf(a[u][i], bv.w, acc[i][3]);
            }
        }
    }

    // Epilogue: C normal [m][n]; lanes contiguous 16B -> fully coalesced
#pragma unroll
    for (int i = 0; i < 16; i++) {
        *(float4*)&C[(size_t)(row0 + i) * N + col0 + lane4] =
            (float4){acc[i][0], acc[i][1], acc[i][2], acc[i][3]};
    }
}

// ---------------------------------------------------------------------------
// K2: per-(b,h) LIF scan; reads z1 [m][h] (strided), writes s1T[h][(b,t)]
// CONTIGUOUS (float4 stores) for G2's uniform A-loads. Ping-pong prefetch.
// Arithmetic identical to round 1 (sequential per element).
// ---------------------------------------------------------------------------
__global__ void lif_scan1(const float* __restrict__ z1,
                          float* __restrict__ s1T,
                          const float* __restrict__ th_p) {
    int gtid = blockIdx.x * blockDim.x + threadIdx.x;   // 0..32767
    int b = gtid >> 9;
    int h = gtid & 511;
    float th = *th_p;
    const float* zp = z1 + (size_t)b * TSTEPS * HDIM + h;
    float* sp = s1T + (size_t)h * MROWS + (size_t)b * TSTEPS;   // t-contiguous
    float m = 0.0f;
    float bufA[16], bufB[16];
#pragma unroll
    for (int i = 0; i < 16; i++) bufA[i] = zp[(size_t)i * HDIM];
    for (int t0 = 0; t0 < TSTEPS; t0 += 32) {
#pragma unroll
        for (int i = 0; i < 16; i++) bufB[i] = zp[(size_t)(t0 + 16 + i) * HDIM];
        {
            float ss[16];
#pragma unroll
            for (int i = 0; i < 16; i++) {
                m += bufA[i];
                float thr = m / th - 1.0f;
                ss[i] = (thr >= 0.0f) ? 1.0f : 0.0f;
                if (thr > 0.0f) m -= th;
            }
#pragma unroll
            for (int v = 0; v < 4; v++)
                *(float4*)&sp[t0 + v * 4] =
                    (float4){ss[v * 4], ss[v * 4 + 1], ss[v * 4 + 2], ss[v * 4 + 3]};
        }
        if (t0 + 32 < TSTEPS) {
#pragma unroll
            for (int i = 0; i < 16; i++) bufA[i] = zp[(size_t)(t0 + 32 + i) * HDIM];
        }
        {
            float ss[16];
#pragma unroll
            for (int i = 0; i < 16; i++) {
                m += bufB[i];
                float thr = m / th - 1.0f;
                ss[i] = (thr >= 0.0f) ? 1.0f : 0.0f;
                if (thr > 0.0f) m -= th;
            }
#pragma unroll
            for (int v = 0; v < 4; v++)
                *(float4*)&sp[t0 + 16 + v * 4] =
                    (float4){ss[v * 4], ss[v * 4 + 1], ss[v * 4 + 2], ss[v * 4 + 3]};
        }
    }
}

// ---------------------------------------------------------------------------
// K4: per-(b,j) scan: m2 = (m2 + raw[t]) + bias, spike/reset -> out.
// Ping-pong prefetch (round-7 version, unchanged).
// ---------------------------------------------------------------------------
__global__ void lif_scan2(const float* __restrict__ raw,
                          const float* __restrict__ b2,
                          const float* __restrict__ th_p,
                          float* __restrict__ out) {
    int gtid = blockIdx.x * blockDim.x + threadIdx.x;   // 0..32767
    int b = gtid >> 9;
    int j = gtid & 511;
    float th = *th_p;
    float bias = b2[j];
    const float* rp = raw + (size_t)b * TSTEPS * HDIM + j;
    float* op = out + (size_t)b * TSTEPS * HDIM + j;
    float m = 0.0f;
    float bufA[16], bufB[16];
#pragma unroll
    for (int i = 0; i < 16; i++) bufA[i] = rp[(size_t)i * HDIM];
    for (int t0 = 0; t0 < TSTEPS; t0 += 32) {
#pragma unroll
        for (int i = 0; i < 16; i++) bufB[i] = rp[(size_t)(t0 + 16 + i) * HDIM];
        {
            float ss[16];
#pragma unroll
            for (int i = 0; i < 16; i++) {
                m = (m + bufA[i]) + bias;
                float thr = m / th - 1.0f;
                ss[i] = (thr >= 0.0f) ? 1.0f : 0.0f;
                if (thr > 0.0f) m -= th;
            }
#pragma unroll
            for (int i = 0; i < 16; i++) op[(size_t)(t0 + i) * HDIM] = ss[i];
        }
        if (t0 + 32 < TSTEPS) {
#pragma unroll
            for (int i = 0; i < 16; i++) bufA[i] = rp[(size_t)(t0 + 32 + i) * HDIM];
        }
        {
            float ss[16];
#pragma unroll
            for (int i = 0; i < 16; i++) {
                m = (m + bufB[i]) + bias;
                float thr = m / th - 1.0f;
                ss[i] = (thr >= 0.0f) ? 1.0f : 0.0f;
                if (thr > 0.0f) m -= th;
            }
#pragma unroll
            for (int i = 0; i < 16; i++) op[(size_t)(t0 + 16 + i) * HDIM] = ss[i];
        }
    }
}

// ---------------------------------------------------------------------------
extern "C" void kernel_launch(void* const* d_in, const int* in_sizes, int n_in,
                              void* d_out, int out_size, void* d_ws, size_t ws_size,
                              hipStream_t stream) {
    const float* x    = (const float*)d_in[0];   // (64, 512, 256)
    const float* c1w  = (const float*)d_in[1];   // (512, 256, 3)
    const float* c1b  = (const float*)d_in[2];   // (512,)
    const float* c2w  = (const float*)d_in[3];   // (512, 512, 3)
    const float* c2b  = (const float*)d_in[4];   // (512,)
    const float* th1  = (const float*)d_in[5];   // scalar
    const float* th2  = (const float*)d_in[6];   // scalar
    float* out = (float*)d_out;                  // (64, 512, 512)

    // Workspace layout (floats):
    //   W1T : 131072   (512 KB)   [k=i][n=h]
    //   W2T : 262144   (1 MB)     [k=h][n=j]
    //   bufA: 16777216 (64 MB)    z1, later m2raw   [m][n]
    //   bufS: 16777216 (64 MB)    s1T               [h][(b,t)]
    float* W1T  = (float*)d_ws;
    float* W2T  = W1T + IDIM * HDIM;
    float* bufA = W2T + HDIM * HDIM;
    float* bufS = bufA + (size_t)MROWS * HDIM;

    // K0: weight extraction
    extract_weights<<<(HDIM * HDIM + 255) / 256, 256, 0, stream>>>(c1w, c2w, W1T, W2T);

    // K1: z1 = x @ W1T + b1   (M=32768, K=256, N=512) -> bufA
    {
        dim3 grid(MROWS / BM1, HDIM / BN1);
        gemm_g1<<<grid, 256, 0, stream>>>(x, W1T, c1b, bufA, IDIM);
    }

    // K2: s1 scan -> bufS (transposed s1T[h][(b,t)])
    lif_scan1<<<MROWS / 64, 64, 0, stream>>>(bufA, bufS, th1);

    // K3: m2raw = s1 @ W2T   (M=32768, K=512, N=512) -> bufA (reg-only GEMM)
    {
        dim3 grid(MROWS / G2_ROWS, HDIM / G2_COLS);
        gemm_g2<<<grid, 64, 0, stream>>>(bufS, W2T, bufA);
    }

    // K4: s2 scan -> out
    lif_scan2<<<MROWS / 64, 64, 0, stream>>>(bufA, c2b, th2, out);
}